// Round 15
// baseline (267.627 us; speedup 1.0000x reference)
//
#include <hip/hip_runtime.h>
#include <hip/hip_cooperative_groups.h>

namespace cg = cooperative_groups;

#define N_NODES 50000
#define N_REL 8
#define N_EDGES 64000
#define D 128
#define TROWS 32
#define NT 1563      // ceil(N_NODES/32)
#define CAP 128      // bucket cap: Poisson mean 41, 13 sigma headroom
#define SLABW 66     // uints per slab row (264 B, 2-way banks = free)
#define GRID 256     // persistent, 1 block/CU (cooperative co-residency)
#define NTHR (GRID * 512)  // 131072

typedef __attribute__((ext_vector_type(8))) short short8;
typedef __attribute__((ext_vector_type(4))) float f32x4;

__device__ __forceinline__ unsigned short f2bf(float x) {
  unsigned int u = __float_as_uint(x);
  u += 0x7FFFu + ((u >> 16) & 1u);
  return (unsigned short)(u >> 16);
}
__device__ __forceinline__ float bflo(unsigned v) { return __uint_as_float(v << 16); }
__device__ __forceinline__ float bfhi(unsigned v) { return __uint_as_float(v & 0xFFFF0000u); }
__device__ __forceinline__ unsigned packbf(float x, float y) {
  return (unsigned)f2bf(x) | ((unsigned)f2bf(y) << 16);
}

// One cooperative kernel, 4 phases:
// P0 zero counters | P1 counts + F/W conv + bias | P2 coeff + bucket place |
// P3 = R7 fused (persistent tiles; wave w = relation w gather + col-slice w GEMM)
__global__ __launch_bounds__(512, 2) void mega_kernel(
    const int* __restrict__ src, const int* __restrict__ dst,
    const float* __restrict__ F, const float* __restrict__ W,
    const float* __restrict__ b, int* __restrict__ outc, int* __restrict__ inc,
    int* __restrict__ bcnt, int2* __restrict__ buckets,
    unsigned* __restrict__ F16, unsigned short* __restrict__ Wt,
    float* __restrict__ bs, float* __restrict__ out) {
  cg::grid_group grid = cg::this_grid();
  __shared__ unsigned slabs[8][TROWS * SLABW];  // 67584 B
  __shared__ int2 dlds[8][CAP];                 // 8192 B
  int tid = threadIdx.x;
  int gtid = blockIdx.x * 512 + tid;

  // ---- P0: zero outc|inc|bcnt (contiguous region based at outc) ----
  const int ZWORDS = 2 * N_REL * N_NODES + N_REL * NT;  // 812504
  for (int i = gtid; i < ZWORDS; i += NTHR) outc[i] = 0;
  grid.sync();

  // ---- P1: degree counts + F->bf16x2 + W->bf16 [r][n][k] + bias sum ----
  for (int e = gtid; e < N_REL * N_EDGES; e += NTHR) {
    int r = e / N_EDGES;
    atomicAdd(&outc[r * N_NODES + src[e]], 1);
    atomicAdd(&inc[r * N_NODES + dst[e]], 1);
  }
  {
    const float4* F4 = (const float4*)F;
    for (int i = gtid; i < N_NODES * 32; i += NTHR) {
      float4 v = F4[i];
      ((uint2*)F16)[i] = make_uint2(packbf(v.x, v.y), packbf(v.z, v.w));
    }
    // N_REL*D*D = 131072 = NTHR exactly: one W element per thread
    int i = gtid;
    int r = i >> 14, rem = i & 16383, n = rem >> 7, k = rem & 127;
    Wt[i] = f2bf(W[(r << 14) + (k << 7) + n]);
    if (gtid < D) {
      float v = 0.f;
#pragma unroll
      for (int rr = 0; rr < N_REL; ++rr) v += b[rr * D + gtid];
      bs[gtid] = v;
    }
  }
  grid.sync();

  // ---- P2: per-edge coeff + bucket place (8B descs, R7 format) ----
  for (int e = gtid; e < N_REL * N_EDGES; e += NTHR) {
    int r = e / N_EDGES;
    int s = src[e], d = dst[e];
    float c = rsqrtf(fmaxf((float)outc[r * N_NODES + s], 1.0f)) *
              rsqrtf(fmaxf((float)inc[r * N_NODES + d], 1.0f));
    int tile = d >> 5;
    int slot = atomicAdd(&bcnt[r * NT + tile], 1);
    if (slot < CAP)
      buckets[(size_t)(r * NT + tile) * CAP + slot] =
          make_int2(s | ((d & 31) << 17), __float_as_int(c));
  }
  grid.sync();

  // ---- P3: R7 fused body (byte-identical structure) ----
  int lane = tid & 63;
  int w = __builtin_amdgcn_readfirstlane(tid >> 6);
  int l15 = lane & 15, g = lane >> 4;

  short8 bfr[8][4];
#pragma unroll
  for (int r = 0; r < 8; ++r)
#pragma unroll
    for (int ks = 0; ks < 4; ++ks)
      bfr[r][ks] = *(const short8*)&Wt[(size_t)r * D * D +
                                       (w * 16 + l15) * D + ks * 32 + g * 8];
  float bias = bs[w * 16 + l15];

#define RMW(dd, fv)                                           \
  {                                                           \
    int row_ = ((dd).x >> 17) & 31;                           \
    unsigned* p_ = &slabs[w][row_ * SLABW + lane];            \
    float c_ = __int_as_float((dd).y);                        \
    unsigned old_ = *p_;                                      \
    float vx_ = fmaf(c_, bflo(fv), bflo(old_));               \
    float vy_ = fmaf(c_, bfhi(fv), bfhi(old_));               \
    *p_ = packbf(vx_, vy_);                                   \
  }

  for (int t = blockIdx.x; t < NT; t += GRID) {
    __syncthreads();  // prior tile's MFMA reads of slabs complete

    for (int i = lane; i < TROWS * SLABW; i += 64) slabs[w][i] = 0u;

    int n = min(bcnt[w * NT + t], CAP);
    const int2* bk = &buckets[(size_t)(w * NT + t) * CAP];
    if (lane < n) dlds[w][lane] = bk[lane];
    if (lane + 64 < n) dlds[w][lane + 64] = bk[lane + 64];

    int i = 0;
    for (; i + 4 <= n; i += 4) {
      int2 d0 = dlds[w][i], d1 = dlds[w][i + 1], d2 = dlds[w][i + 2],
           d3 = dlds[w][i + 3];
      unsigned f0 = F16[(unsigned)(d0.x & 0x1FFFF) * 64 + lane];
      unsigned f1 = F16[(unsigned)(d1.x & 0x1FFFF) * 64 + lane];
      unsigned f2 = F16[(unsigned)(d2.x & 0x1FFFF) * 64 + lane];
      unsigned f3 = F16[(unsigned)(d3.x & 0x1FFFF) * 64 + lane];
      RMW(d0, f0) RMW(d1, f1) RMW(d2, f2) RMW(d3, f3)
    }
    for (; i < n; ++i) {
      int2 dd = dlds[w][i];
      unsigned fv = F16[(unsigned)(dd.x & 0x1FFFF) * 64 + lane];
      RMW(dd, fv)
    }

    __syncthreads();  // all 8 slabs ready

    f32x4 a0 = (f32x4){0.f, 0.f, 0.f, 0.f};
    f32x4 a1 = (f32x4){0.f, 0.f, 0.f, 0.f};
#pragma unroll
    for (int r = 0; r < 8; ++r) {
#pragma unroll
      for (int ks = 0; ks < 4; ++ks) {
        short8 A0 = *(const short8*)&slabs[r][l15 * SLABW + ks * 16 + g * 4];
        short8 A1 =
            *(const short8*)&slabs[r][(16 + l15) * SLABW + ks * 16 + g * 4];
        a0 = __builtin_amdgcn_mfma_f32_16x16x32_bf16(A0, bfr[r][ks], a0, 0, 0, 0);
        a1 = __builtin_amdgcn_mfma_f32_16x16x32_bf16(A1, bfr[r][ks], a1, 0, 0, 0);
      }
    }

    int t0 = t * TROWS;
    int col = w * 16 + l15;
#pragma unroll
    for (int q = 0; q < 4; ++q) {
      int row0 = t0 + g * 4 + q;
      if (row0 < N_NODES) out[(size_t)row0 * D + col] = a0[q] + bias;
      int row1 = t0 + 16 + g * 4 + q;
      if (row1 < N_NODES) out[(size_t)row1 * D + col] = a1[q] + bias;
    }
  }
#undef RMW
}

extern "C" void kernel_launch(void* const* d_in, const int* in_sizes, int n_in,
                              void* d_out, int out_size, void* d_ws, size_t ws_size,
                              hipStream_t stream) {
  const int* src = (const int*)d_in[3];    // [8,64000]
  const int* dst = (const int*)d_in[4];    // [8,64000]
  const float* F = (const float*)d_in[0];  // [50000,128]
  const float* W = (const float*)d_in[1];  // [8,128,128]
  const float* b = (const float*)d_in[2];  // [8,128]
  float* out = (float*)d_out;              // [50000,128]

  char* ws = (char*)d_ws;
  size_t o = 0;
  int* outc = (int*)(ws + o);  o += (size_t)N_REL * N_NODES * 4;  // 1.6 MB
  int* inc = (int*)(ws + o);   o += (size_t)N_REL * N_NODES * 4;  // 1.6 MB
  int* bcnt = (int*)(ws + o);  o += (size_t)N_REL * NT * 4;       // 50 KB (contig w/ above)
  int2* buckets = (int2*)(ws + o);                o += (size_t)N_REL * NT * CAP * 8;  // 12.8 MB
  unsigned* F16 = (unsigned*)(ws + o);            o += (size_t)N_NODES * 64 * 4;      // 12.8 MB
  unsigned short* Wt = (unsigned short*)(ws + o); o += (size_t)N_REL * D * D * 2;
  float* bs = (float*)(ws + o);                   o += D * 4;

  void* args[] = {(void*)&src, (void*)&dst, (void*)&F,    (void*)&W,
                  (void*)&b,   (void*)&outc, (void*)&inc, (void*)&bcnt,
                  (void*)&buckets, (void*)&F16, (void*)&Wt, (void*)&bs,
                  (void*)&out};
  hipLaunchCooperativeKernel((void*)mega_kernel, dim3(GRID), dim3(512), args, 0,
                             stream);
}